// Round 10
// baseline (264.431 us; speedup 1.0000x reference)
//
#include <hip/hip_runtime.h>
#include <stdint.h>

typedef __attribute__((ext_vector_type(8))) short bf16x8;
typedef __attribute__((ext_vector_type(4))) float f32x4;
typedef __attribute__((ext_vector_type(4))) uint32_t u32x4;

__device__ __forceinline__ float bf2f(uint16_t u) {
    union { uint32_t u; float f; } c; c.u = ((uint32_t)u) << 16; return c.f;
}
__device__ __forceinline__ uint16_t f2bf(float f) {
    union { float f; uint32_t u; } c; c.f = f;
    uint32_t r = c.u + 0x7fffu + ((c.u >> 16) & 1u);
    return (uint16_t)(r >> 16);
}
__device__ __forceinline__ uint32_t pk2bf(float a, float b) {
#if __has_builtin(__builtin_amdgcn_cvt_pk_bf16_f32)
    auto v = __builtin_amdgcn_cvt_pk_bf16_f32(a, b);
    uint32_t u; __builtin_memcpy(&u, &v, 4); return u;
#else
    return (uint32_t)f2bf(a) | ((uint32_t)f2bf(b) << 16);
#endif
}

// async global->LDS, 16B/lane; LDS dest must be wave-uniform base + lane*16.
__device__ __forceinline__ void gld_lds16(const uint16_t* g, uint16_t* l) {
    __builtin_amdgcn_global_load_lds(
        (const __attribute__((address_space(1))) void*)g,
        (__attribute__((address_space(3))) void*)l, 16, 0, 0);
}

// ---------------------------------------------------------------------------
// Single fused prep: 6 weight transposes (blocks 0..2047), x convert
// (blocks 2048..6143), bias converts (blocks 6144..6157). Block = (32,8).
// ---------------------------------------------------------------------------
__global__ void prep_all(const float* __restrict__ x,
                         const float* __restrict__ W1, const float* __restrict__ W2,
                         const float* __restrict__ Wq, const float* __restrict__ Wk,
                         const float* __restrict__ Wv, const float* __restrict__ Wo,
                         const float* __restrict__ b1, const float* __restrict__ b2,
                         const float* __restrict__ bq, const float* __restrict__ bk,
                         const float* __restrict__ bv, const float* __restrict__ bo,
                         uint16_t* __restrict__ W1T, uint16_t* __restrict__ W2T,
                         uint16_t* __restrict__ WqkvT, uint16_t* __restrict__ WoT,
                         uint16_t* __restrict__ xb, uint16_t* __restrict__ bbase)
{
    const int id = blockIdx.x;
    const int tx = threadIdx.x, ty = threadIdx.y;
    const int tid = ty * 32 + tx;
    if (id < 2048) {            // weight transpose tiles
        __shared__ uint16_t t[32][33];
        const float* src; uint16_t* dst; int R, C, tile;
        if      (id < 512)  { src = W1; dst = W1T;              R = 512;  C = 1024; tile = id; }
        else if (id < 1024) { src = W2; dst = W2T;              R = 1024; C = 512;  tile = id - 512; }
        else if (id < 1280) { src = Wq; dst = WqkvT;            R = 512;  C = 512;  tile = id - 1024; }
        else if (id < 1536) { src = Wk; dst = WqkvT + 512*512;  R = 512;  C = 512;  tile = id - 1280; }
        else if (id < 1792) { src = Wv; dst = WqkvT + 1024*512; R = 512;  C = 512;  tile = id - 1536; }
        else                { src = Wo; dst = WoT;              R = 512;  C = 512;  tile = id - 1792; }
        const int ntx = C / 32;
        const int bx = (tile % ntx) * 32, by = (tile / ntx) * 32;
#pragma unroll
        for (int i = ty; i < 32; i += 8) t[i][tx] = f2bf(src[(size_t)(by + i) * C + bx + tx]);
        __syncthreads();
#pragma unroll
        for (int i = ty; i < 32; i += 8) dst[(size_t)(bx + i) * R + by + tx] = t[tx][i];
    } else if (id < 6144) {     // x convert, float4-vectorized
        int i = (id - 2048) * 256 + tid;   // < 1048576
        float4 v = ((const float4*)x)[i];
        ushort4 o;
        o.x = f2bf(v.x); o.y = f2bf(v.y); o.z = f2bf(v.z); o.w = f2bf(v.w);
        ((ushort4*)xb)[i] = o;
    } else {                    // bias converts: [b1|b2|bq|bk|bv|bo] = 3584 u16
        int i = (id - 6144) * 256 + tid;
        if      (i < 1024) bbase[i] = f2bf(b1[i]);
        else if (i < 1536) bbase[i] = f2bf(b2[i - 1024]);
        else if (i < 2048) bbase[i] = f2bf(bq[i - 1536]);
        else if (i < 2560) bbase[i] = f2bf(bk[i - 2048]);
        else if (i < 3072) bbase[i] = f2bf(bv[i - 2560]);
        else if (i < 3584) bbase[i] = f2bf(bo[i - 3072]);
    }
}

// ---------------------------------------------------------------------------
// Staged GEMM 128x128 (m97 lineage): C = act(A[M,K] @ Bt[N,K]^T + bias)
// ---------------------------------------------------------------------------
template<int RELU, int F32OUT>
__global__ __launch_bounds__(256)
void gemm_k(const uint16_t* __restrict__ A, const uint16_t* __restrict__ Bt,
            const uint16_t* __restrict__ bias, void* __restrict__ Cv,
            int M, int N, int K)
{
    __shared__ __align__(16) uint16_t lsA[128 * 32];
    __shared__ __align__(16) uint16_t lsB[128 * 32];

    const int tid = threadIdx.x, lane = tid & 63, wid = tid >> 6;
    const int quad = lane >> 4, lm = lane & 15;
    const int wm = wid >> 1, wn = wid & 1;
    const int m0 = blockIdx.y * 128, n0 = blockIdx.x * 128;

    f32x4 acc[4][4];
#pragma unroll
    for (int i = 0; i < 4; ++i)
#pragma unroll
        for (int j = 0; j < 4; ++j) acc[i][j] = (f32x4){0.f, 0.f, 0.f, 0.f};

    const int row0 = tid >> 2, row1 = (256 + tid) >> 2, cg = tid & 3;

    for (int k0 = 0; k0 < K; k0 += 32) {
        __syncthreads();
        gld_lds16(A  + (size_t)(m0 + row0) * K + k0 + cg * 8, lsA + (size_t)tid * 8);
        gld_lds16(A  + (size_t)(m0 + row1) * K + k0 + cg * 8, lsA + (size_t)(256 + tid) * 8);
        gld_lds16(Bt + (size_t)(n0 + row0) * K + k0 + cg * 8, lsB + (size_t)tid * 8);
        gld_lds16(Bt + (size_t)(n0 + row1) * K + k0 + cg * 8, lsB + (size_t)(256 + tid) * 8);
        __syncthreads();

        bf16x8 af[4], bfr[4];
#pragma unroll
        for (int t = 0; t < 4; ++t) {
            af[t]  = *(const bf16x8*)(lsA + (wm * 64 + t * 16 + lm) * 32 + quad * 8);
            bfr[t] = *(const bf16x8*)(lsB + (wn * 64 + t * 16 + lm) * 32 + quad * 8);
        }
#pragma unroll
        for (int i = 0; i < 4; ++i)
#pragma unroll
            for (int j = 0; j < 4; ++j)
                acc[i][j] = __builtin_amdgcn_mfma_f32_16x16x32_bf16(af[i], bfr[j], acc[i][j], 0, 0, 0);
    }

#pragma unroll
    for (int i = 0; i < 4; ++i) {
        const int r0 = m0 + wm * 64 + i * 16 + quad * 4;
#pragma unroll
        for (int j = 0; j < 4; ++j) {
            const int col = n0 + wn * 64 + j * 16 + lm;
            const float bvj = bf2f(bias[col]);
#pragma unroll
            for (int r = 0; r < 4; ++r) {
                float v = acc[i][j][r] + bvj;
                if (RELU) v = fmaxf(v, 0.f);
                if (F32OUT) ((float*)Cv)[(size_t)(r0 + r) * N + col] = v;
                else        ((uint16_t*)Cv)[(size_t)(r0 + r) * N + col] = f2bf(v);
            }
        }
    }
}

// ---------------------------------------------------------------------------
// Staged GEMM 64x128 tile (small-N GEMMs -> 2 blocks/CU)
// ---------------------------------------------------------------------------
template<int RELU, int F32OUT>
__global__ __launch_bounds__(256)
void gemm_k64(const uint16_t* __restrict__ A, const uint16_t* __restrict__ Bt,
              const uint16_t* __restrict__ bias, void* __restrict__ Cv,
              int M, int N, int K)
{
    __shared__ __align__(16) uint16_t lsA[64 * 32];
    __shared__ __align__(16) uint16_t lsB[128 * 32];

    const int tid = threadIdx.x, lane = tid & 63, wid = tid >> 6;
    const int quad = lane >> 4, lm = lane & 15;
    const int wm = wid >> 1, wn = wid & 1;
    const int m0 = blockIdx.y * 64, n0 = blockIdx.x * 128;

    f32x4 acc[2][4];
#pragma unroll
    for (int i = 0; i < 2; ++i)
#pragma unroll
        for (int j = 0; j < 4; ++j) acc[i][j] = (f32x4){0.f, 0.f, 0.f, 0.f};

    const int rowA = tid >> 2;
    const int rowB0 = tid >> 2, rowB1 = (256 + tid) >> 2, cg = tid & 3;

    for (int k0 = 0; k0 < K; k0 += 32) {
        __syncthreads();
        gld_lds16(A  + (size_t)(m0 + rowA) * K + k0 + cg * 8, lsA + (size_t)tid * 8);
        gld_lds16(Bt + (size_t)(n0 + rowB0) * K + k0 + cg * 8, lsB + (size_t)tid * 8);
        gld_lds16(Bt + (size_t)(n0 + rowB1) * K + k0 + cg * 8, lsB + (size_t)(256 + tid) * 8);
        __syncthreads();

        bf16x8 af[2], bfr[4];
#pragma unroll
        for (int t = 0; t < 2; ++t)
            af[t] = *(const bf16x8*)(lsA + (wm * 32 + t * 16 + lm) * 32 + quad * 8);
#pragma unroll
        for (int t = 0; t < 4; ++t)
            bfr[t] = *(const bf16x8*)(lsB + (wn * 64 + t * 16 + lm) * 32 + quad * 8);
#pragma unroll
        for (int i = 0; i < 2; ++i)
#pragma unroll
            for (int j = 0; j < 4; ++j)
                acc[i][j] = __builtin_amdgcn_mfma_f32_16x16x32_bf16(af[i], bfr[j], acc[i][j], 0, 0, 0);
    }

#pragma unroll
    for (int i = 0; i < 2; ++i) {
        const int r0 = m0 + wm * 32 + i * 16 + quad * 4;
#pragma unroll
        for (int j = 0; j < 4; ++j) {
            const int col = n0 + wn * 64 + j * 16 + lm;
            const float bvj = bf2f(bias[col]);
#pragma unroll
            for (int r = 0; r < 4; ++r) {
                float v = acc[i][j][r] + bvj;
                if (RELU) v = fmaxf(v, 0.f);
                if (F32OUT) ((float*)Cv)[(size_t)(r0 + r) * N + col] = v;
                else        ((uint16_t*)Cv)[(size_t)(r0 + r) * N + col] = f2bf(v);
            }
        }
    }
}

// ---------------------------------------------------------------------------
// Staged QKV GEMM: parts 0,1 (Q,K) -> qk[8192][1024]; part 2 (V) -> Vt
// transposed AND key-permuted per 128-tile: pos = (k&15)*8 + ((k&127)>>4).
// ---------------------------------------------------------------------------
__global__ __launch_bounds__(256)
void gemm_qkv_s(const uint16_t* __restrict__ A, const uint16_t* __restrict__ Bt,
                const uint16_t* __restrict__ bq, const uint16_t* __restrict__ bk,
                const uint16_t* __restrict__ bv_,
                uint16_t* __restrict__ qk, uint16_t* __restrict__ Vt)
{
    __shared__ __align__(16) uint16_t lsA[128 * 32];
    __shared__ __align__(16) uint16_t lsB[128 * 32];

    const int tid = threadIdx.x, lane = tid & 63, wid = tid >> 6;
    const int quad = lane >> 4, lm = lane & 15;
    const int wm = wid >> 1, wn = wid & 1;
    const int m0 = blockIdx.y * 128, n0 = blockIdx.x * 128;
    const int part = n0 >> 9;
    const uint16_t* B = (part == 0) ? bq : (part == 1) ? bk : bv_;
    const int K = 512;

    f32x4 acc[4][4];
#pragma unroll
    for (int i = 0; i < 4; ++i)
#pragma unroll
        for (int j = 0; j < 4; ++j) acc[i][j] = (f32x4){0.f, 0.f, 0.f, 0.f};

    const int row0 = tid >> 2, row1 = (256 + tid) >> 2, cg = tid & 3;

    for (int k0 = 0; k0 < K; k0 += 32) {
        __syncthreads();
        gld_lds16(A  + (size_t)(m0 + row0) * K + k0 + cg * 8, lsA + (size_t)tid * 8);
        gld_lds16(A  + (size_t)(m0 + row1) * K + k0 + cg * 8, lsA + (size_t)(256 + tid) * 8);
        gld_lds16(Bt + (size_t)(n0 + row0) * K + k0 + cg * 8, lsB + (size_t)tid * 8);
        gld_lds16(Bt + (size_t)(n0 + row1) * K + k0 + cg * 8, lsB + (size_t)(256 + tid) * 8);
        __syncthreads();

        bf16x8 af[4], bfr[4];
#pragma unroll
        for (int t = 0; t < 4; ++t) {
            af[t]  = *(const bf16x8*)(lsA + (wm * 64 + t * 16 + lm) * 32 + quad * 8);
            bfr[t] = *(const bf16x8*)(lsB + (wn * 64 + t * 16 + lm) * 32 + quad * 8);
        }
#pragma unroll
        for (int i = 0; i < 4; ++i)
#pragma unroll
            for (int j = 0; j < 4; ++j)
                acc[i][j] = __builtin_amdgcn_mfma_f32_16x16x32_bf16(af[i], bfr[j], acc[i][j], 0, 0, 0);
    }

#pragma unroll
    for (int i = 0; i < 4; ++i) {
        const int mb = m0 + wm * 64 + i * 16 + quad * 4;
#pragma unroll
        for (int j = 0; j < 4; ++j) {
            const int nl = (n0 & 511) + wn * 64 + j * 16 + lm;
            const float bvj = bf2f(B[nl]);
            if (part < 2) {
#pragma unroll
                for (int r = 0; r < 4; ++r)
                    qk[(size_t)(mb + r) * 1024 + part * 512 + nl] = f2bf(acc[i][j][r] + bvj);
            } else {
                const int h = nl >> 6, d = nl & 63;
                const int b = mb >> 11, s0 = mb & 2047;
                const size_t rowbase = ((size_t)(((b << 3) | h)) * 64 + d) * 2048;
#pragma unroll
                for (int r = 0; r < 4; ++r) {
                    const int k = s0 + r;
                    const int kk = k & 127;
                    const int pos = (k & ~127) | (((kk & 15) << 3) | (kk >> 4));
                    Vt[rowbase + pos] = f2bf(acc[i][j][r] + bvj);
                }
            }
        }
    }
}

// ---------------------------------------------------------------------------
// Flash attention, inverse band mask (|i-j|<=5 excluded). Fixed-scale softmax.
// Grid (16, 32): 128 q-rows/block, 4 waves; wave w owns q-rows [w*32, w*32+32).
// Key-permuted P/V storage (pos = (k&15)*8 + (k>>4) within each 128-tile):
// P spill is one ds_write_b128 per (i,r) (lane lm owns 8 contiguous slots).
// LDS: union{ lsK [128][72] | lsP [128][136] } + lsV [64][136] = 51 KiB.
// ---------------------------------------------------------------------------
__global__ __launch_bounds__(256, 2)
void attn_k(const uint16_t* __restrict__ qk, const uint16_t* __restrict__ Vt,
            uint16_t* __restrict__ Out)
{
    __shared__ __align__(16) uint16_t lsKP[128 * 136];  // K view stride 72 / P view stride 136
    __shared__ __align__(16) uint16_t lsV[64 * 136];

    const int tid = threadIdx.x, lane = tid & 63, wid = tid >> 6;
    const int quad = lane >> 4, lm = lane & 15;
    const int bh = blockIdx.y, b = bh >> 3, h = bh & 7;
    const int q0 = blockIdx.x * 128;
    const float cscale = 0.125f * 1.44269504088896f;   // (1/sqrt(64))*log2(e)

    // Q fragments (wave-private 32 rows = 2 m-tiles), pre-scaled into log2 domain
    bf16x8 qf[2][2];
#pragma unroll
    for (int i = 0; i < 2; ++i)
#pragma unroll
        for (int ks = 0; ks < 2; ++ks) {
            bf16x8 q = *(const bf16x8*)(qk +
                (size_t)(b * 2048 + q0 + wid * 32 + i * 16 + lm) * 1024 + h * 64 + ks * 32 + quad * 8);
#pragma unroll
            for (int e = 0; e < 8; ++e)
                q[e] = (short)f2bf(bf2f((uint16_t)q[e]) * cscale);
            qf[i][ks] = q;
        }

    f32x4 oacc[2][4];
#pragma unroll
    for (int i = 0; i < 2; ++i)
#pragma unroll
        for (int n = 0; n < 4; ++n) oacc[i][n] = (f32x4){0.f, 0.f, 0.f, 0.f};
    float lrow[2][4];
#pragma unroll
    for (int i = 0; i < 2; ++i)
#pragma unroll
        for (int r = 0; r < 4; ++r) lrow[i][r] = 0.f;

    for (int j0 = 0; j0 < 2048; j0 += 128) {
        __syncthreads();   // prev-iter lsP/lsV reads done before restaging
        // stage K [128 keys][64 d] -> lsKP stride 72 (16B-aligned rows)
#pragma unroll
        for (int c = 0; c < 4; ++c) {
            const int chunk = c * 256 + tid;
            const int s = chunk >> 3, cg = chunk & 7;
            *(bf16x8*)(lsKP + s * 72 + cg * 8) =
                *(const bf16x8*)(qk + (size_t)(b * 2048 + j0 + s) * 1024 + 512 + h * 64 + cg * 8);
        }
        // stage V (already key-permuted in global) [64 d][128 pos] -> lsV stride 136
#pragma unroll
        for (int c = 0; c < 4; ++c) {
            const int chunk = c * 256 + tid;
            const int d = chunk >> 4, cg2 = chunk & 15;
            *(bf16x8*)(lsV + d * 136 + cg2 * 8) =
                *(const bf16x8*)(Vt + (size_t)(bh * 64 + d) * 2048 + j0 + cg2 * 8);
        }
        __syncthreads();

        // S = Q K^T  (2 q-tiles x 8 key-tiles x 2 k-steps)
        f32x4 sacc[2][8];
#pragma unroll
        for (int i = 0; i < 2; ++i)
#pragma unroll
            for (int j = 0; j < 8; ++j) sacc[i][j] = (f32x4){0.f, 0.f, 0.f, 0.f};
#pragma unroll
        for (int ks = 0; ks < 2; ++ks)
#pragma unroll
            for (int j = 0; j < 8; ++j) {
                bf16x8 kf = *(const bf16x8*)(lsKP + (j * 16 + lm) * 72 + ks * 32 + quad * 8);
#pragma unroll
                for (int i = 0; i < 2; ++i)
                    sacc[i][j] = __builtin_amdgcn_mfma_f32_16x16x32_bf16(qf[i][ks], kf, sacc[i][j], 0, 0, 0);
            }

        // band mask (uniform branch; hits <=2 j0-tiles per block)
        if ((j0 + 127 >= q0 - 5) && (j0 <= q0 + 127 + 5)) {
#pragma unroll
            for (int i = 0; i < 2; ++i)
#pragma unroll
                for (int j = 0; j < 8; ++j)
#pragma unroll
                    for (int r = 0; r < 4; ++r) {
                        int qr = q0 + wid * 32 + i * 16 + quad * 4 + r;
                        int kc = j0 + j * 16 + lm;
                        int dd = qr - kc; if (dd < 0) dd = -dd;
                        if (dd <= 5) sacc[i][j][r] = -1e30f;
                    }
        }

        __syncthreads();   // all kf reads done before P overwrites the union

        // p = exp2(s); accumulate l; write P permuted: lane lm's 8 values (keys
        // j*16+lm, j=0..7) land at contiguous slots lm*8+j -> one b128 store.
#pragma unroll
        for (int i = 0; i < 2; ++i)
#pragma unroll
            for (int r = 0; r < 4; ++r) {
                const int prow = wid * 32 + i * 16 + quad * 4 + r;
                float p[8], rs = 0.f;
#pragma unroll
                for (int j = 0; j < 8; ++j) { p[j] = exp2f(sacc[i][j][r]); rs += p[j]; }
                lrow[i][r] += rs;
                u32x4 w;
#pragma unroll
                for (int jp = 0; jp < 4; ++jp) w[jp] = pk2bf(p[2 * jp], p[2 * jp + 1]);
                *(u32x4*)(lsKP + prow * 136 + lm * 8) = w;
            }
        // no barrier: P rows are wave-private; in-wave ordering via lgkmcnt

        // O += P V  (both operands in permuted key space; same bijection -> exact)
#pragma unroll
        for (int ks = 0; ks < 4; ++ks) {
            bf16x8 pa[2];
#pragma unroll
            for (int i = 0; i < 2; ++i)
                pa[i] = *(const bf16x8*)(lsKP + (wid * 32 + i * 16 + lm) * 136 + ks * 32 + quad * 8);
#pragma unroll
            for (int n = 0; n < 4; ++n) {
                bf16x8 vf = *(const bf16x8*)(lsV + (n * 16 + lm) * 136 + ks * 32 + quad * 8);
#pragma unroll
                for (int i = 0; i < 2; ++i)
                    oacc[i][n] = __builtin_amdgcn_mfma_f32_16x16x32_bf16(pa[i], vf, oacc[i][n], 0, 0, 0);
            }
        }
    }

#pragma unroll
    for (int i = 0; i < 2; ++i)
#pragma unroll
        for (int r = 0; r < 4; ++r) {
            float l = lrow[i][r];
            l += __shfl_xor(l, 1, 16);
            l += __shfl_xor(l, 2, 16);
            l += __shfl_xor(l, 4, 16);
            l += __shfl_xor(l, 8, 16);
            const float inv = 1.f / (l + 1e-30f);
            const int s = q0 + wid * 32 + i * 16 + quad * 4 + r;
#pragma unroll
            for (int n = 0; n < 4; ++n)
                Out[(size_t)(b * 2048 + s) * 512 + h * 64 + n * 16 + lm] = f2bf(oacc[i][n][r] * inv);
        }
}

// ---------------------------------------------------------------------------
// Launch — fp32 in, fp32 out; ws peak 37 MiB; 6 dispatches total
// ---------------------------------------------------------------------------
extern "C" void kernel_launch(void* const* d_in, const int* in_sizes, int n_in,
                              void* d_out, int out_size, void* d_ws, size_t ws_size,
                              hipStream_t stream)
{
    const float* x  = (const float*)d_in[0];
    const float* W1 = (const float*)d_in[1];
    const float* b1 = (const float*)d_in[2];
    const float* W2 = (const float*)d_in[3];
    const float* b2 = (const float*)d_in[4];
    const float* Wq = (const float*)d_in[5];
    const float* bq = (const float*)d_in[6];
    const float* Wk = (const float*)d_in[7];
    const float* bk = (const float*)d_in[8];
    const float* Wv = (const float*)d_in[9];
    const float* bv = (const float*)d_in[10];
    const float* Wo = (const float*)d_in[11];
    const float* bo = (const float*)d_in[12];
    (void)in_sizes; (void)n_in; (void)out_size; (void)ws_size;

    char* ws = (char*)d_ws;
    const size_t MiB = 1024 * 1024;
    uint16_t* xb    = (uint16_t*)(ws + 0);                       // 8 MiB [dead after G1]
    uint16_t* W1T   = (uint16_t*)(ws + 8 * MiB);                 // 1 MiB  [1024][512]
    uint16_t* W2T   = (uint16_t*)(ws + 9 * MiB);                 // 1 MiB  [512][1024]
    uint16_t* WqkvT = (uint16_t*)(ws + 10 * MiB);                // 1.5 MiB [1536][512]
    uint16_t* WoT   = (uint16_t*)(ws + 11 * MiB + 512 * 1024);   // 0.5 MiB [512][512]
    uint16_t* bbase = (uint16_t*)(ws + 12 * MiB);                // 3584 u16
    uint16_t* b1b = bbase, *b2b = bbase + 1024, *bqb = bbase + 1536;
    uint16_t* bkb = bbase + 2048, *bvb = bbase + 2560, *bob = bbase + 3072;
    uint16_t* xm1   = (uint16_t*)(ws + 13 * MiB);                // 16 MiB [13,29)
    uint16_t* xm    = (uint16_t*)(ws + 29 * MiB);                //  8 MiB [29,37)
    uint16_t* qk    = xm1;   // aliases xm1 (dead after G2)
    uint16_t* att   = xm;    // aliases xm  (dead after QKV gemm)
    uint16_t* Vt    = xb;    // aliases xb  (dead after G1)

    prep_all<<<6158, dim3(32, 8), 0, stream>>>(x, W1, W2, Wq, Wk, Wv, Wo,
                                               b1, b2, bq, bk, bv, bo,
                                               W1T, W2T, WqkvT, WoT, xb, bbase);

    gemm_k<1,0>  <<<dim3(8, 64),  256, 0, stream>>>(xb,  W1T, b1b, xm1, 8192, 1024, 512);
    gemm_k64<0,0><<<dim3(4, 128), 256, 0, stream>>>(xm1, W2T, b2b, xm,  8192, 512, 1024);
    gemm_qkv_s   <<<dim3(12, 64), 256, 0, stream>>>(xm, WqkvT, bqb, bkb, bvb, qk, Vt);
    attn_k       <<<dim3(16, 32), 256, 0, stream>>>(qk, Vt, att);
    gemm_k64<0,1><<<dim3(4, 128), 256, 0, stream>>>(att, WoT, bob, d_out, 8192, 512, 512);
}

// Round 11
// 251.266 us; speedup vs baseline: 1.0524x; 1.0524x over previous
//
#include <hip/hip_runtime.h>
#include <stdint.h>

typedef __attribute__((ext_vector_type(8))) short bf16x8;
typedef __attribute__((ext_vector_type(4))) float f32x4;

__device__ __forceinline__ float bf2f(uint16_t u) {
    union { uint32_t u; float f; } c; c.u = ((uint32_t)u) << 16; return c.f;
}
__device__ __forceinline__ uint16_t f2bf(float f) {
    union { float f; uint32_t u; } c; c.f = f;
    uint32_t r = c.u + 0x7fffu + ((c.u >> 16) & 1u);
    return (uint16_t)(r >> 16);
}
__device__ __forceinline__ uint32_t pk2bf(float a, float b) {
#if __has_builtin(__builtin_amdgcn_cvt_pk_bf16_f32)
    auto v = __builtin_amdgcn_cvt_pk_bf16_f32(a, b);
    uint32_t u; __builtin_memcpy(&u, &v, 4); return u;
#else
    return (uint32_t)f2bf(a) | ((uint32_t)f2bf(b) << 16);
#endif
}

// async global->LDS, 16B/lane; LDS dest must be wave-uniform base + lane*16.
__device__ __forceinline__ void gld_lds16(const uint16_t* g, uint16_t* l) {
    __builtin_amdgcn_global_load_lds(
        (const __attribute__((address_space(1))) void*)g,
        (__attribute__((address_space(3))) void*)l, 16, 0, 0);
}

// ---------------------------------------------------------------------------
// Single fused prep: 6 weight transposes (blocks 0..2047), x convert
// (blocks 2048..6143), bias converts (blocks 6144..6157). Block = (32,8).
// ---------------------------------------------------------------------------
__global__ void prep_all(const float* __restrict__ x,
                         const float* __restrict__ W1, const float* __restrict__ W2,
                         const float* __restrict__ Wq, const float* __restrict__ Wk,
                         const float* __restrict__ Wv, const float* __restrict__ Wo,
                         const float* __restrict__ b1, const float* __restrict__ b2,
                         const float* __restrict__ bq, const float* __restrict__ bk,
                         const float* __restrict__ bv, const float* __restrict__ bo,
                         uint16_t* __restrict__ W1T, uint16_t* __restrict__ W2T,
                         uint16_t* __restrict__ WqkvT, uint16_t* __restrict__ WoT,
                         uint16_t* __restrict__ xb, uint16_t* __restrict__ bbase)
{
    const int id = blockIdx.x;
    const int tx = threadIdx.x, ty = threadIdx.y;
    const int tid = ty * 32 + tx;
    if (id < 2048) {            // weight transpose tiles
        __shared__ uint16_t t[32][33];
        const float* src; uint16_t* dst; int R, C, tile;
        if      (id < 512)  { src = W1; dst = W1T;              R = 512;  C = 1024; tile = id; }
        else if (id < 1024) { src = W2; dst = W2T;              R = 1024; C = 512;  tile = id - 512; }
        else if (id < 1280) { src = Wq; dst = WqkvT;            R = 512;  C = 512;  tile = id - 1024; }
        else if (id < 1536) { src = Wk; dst = WqkvT + 512*512;  R = 512;  C = 512;  tile = id - 1280; }
        else if (id < 1792) { src = Wv; dst = WqkvT + 1024*512; R = 512;  C = 512;  tile = id - 1536; }
        else                { src = Wo; dst = WoT;              R = 512;  C = 512;  tile = id - 1792; }
        const int ntx = C / 32;
        const int bx = (tile % ntx) * 32, by = (tile / ntx) * 32;
#pragma unroll
        for (int i = ty; i < 32; i += 8) t[i][tx] = f2bf(src[(size_t)(by + i) * C + bx + tx]);
        __syncthreads();
#pragma unroll
        for (int i = ty; i < 32; i += 8) dst[(size_t)(bx + i) * R + by + tx] = t[tx][i];
    } else if (id < 6144) {     // x convert, float4-vectorized
        int i = (id - 2048) * 256 + tid;   // < 1048576
        float4 v = ((const float4*)x)[i];
        ushort4 o;
        o.x = f2bf(v.x); o.y = f2bf(v.y); o.z = f2bf(v.z); o.w = f2bf(v.w);
        ((ushort4*)xb)[i] = o;
    } else {                    // bias converts: [b1|b2|bq|bk|bv|bo] = 3584 u16
        int i = (id - 6144) * 256 + tid;
        if      (i < 1024) bbase[i] = f2bf(b1[i]);
        else if (i < 1536) bbase[i] = f2bf(b2[i - 1024]);
        else if (i < 2048) bbase[i] = f2bf(bq[i - 1536]);
        else if (i < 2560) bbase[i] = f2bf(bk[i - 2048]);
        else if (i < 3072) bbase[i] = f2bf(bv[i - 2560]);
        else if (i < 3584) bbase[i] = f2bf(bo[i - 3072]);
    }
}

// ---------------------------------------------------------------------------
// Staged GEMM 128x128 (m97 lineage): C = act(A[M,K] @ Bt[N,K]^T + bias)
// ---------------------------------------------------------------------------
template<int RELU, int F32OUT>
__global__ __launch_bounds__(256)
void gemm_k(const uint16_t* __restrict__ A, const uint16_t* __restrict__ Bt,
            const uint16_t* __restrict__ bias, void* __restrict__ Cv,
            int M, int N, int K)
{
    __shared__ __align__(16) uint16_t lsA[128 * 32];
    __shared__ __align__(16) uint16_t lsB[128 * 32];

    const int tid = threadIdx.x, lane = tid & 63, wid = tid >> 6;
    const int quad = lane >> 4, lm = lane & 15;
    const int wm = wid >> 1, wn = wid & 1;
    const int m0 = blockIdx.y * 128, n0 = blockIdx.x * 128;

    f32x4 acc[4][4];
#pragma unroll
    for (int i = 0; i < 4; ++i)
#pragma unroll
        for (int j = 0; j < 4; ++j) acc[i][j] = (f32x4){0.f, 0.f, 0.f, 0.f};

    const int row0 = tid >> 2, row1 = (256 + tid) >> 2, cg = tid & 3;

    for (int k0 = 0; k0 < K; k0 += 32) {
        __syncthreads();
        gld_lds16(A  + (size_t)(m0 + row0) * K + k0 + cg * 8, lsA + (size_t)tid * 8);
        gld_lds16(A  + (size_t)(m0 + row1) * K + k0 + cg * 8, lsA + (size_t)(256 + tid) * 8);
        gld_lds16(Bt + (size_t)(n0 + row0) * K + k0 + cg * 8, lsB + (size_t)tid * 8);
        gld_lds16(Bt + (size_t)(n0 + row1) * K + k0 + cg * 8, lsB + (size_t)(256 + tid) * 8);
        __syncthreads();

        bf16x8 af[4], bfr[4];
#pragma unroll
        for (int t = 0; t < 4; ++t) {
            af[t]  = *(const bf16x8*)(lsA + (wm * 64 + t * 16 + lm) * 32 + quad * 8);
            bfr[t] = *(const bf16x8*)(lsB + (wn * 64 + t * 16 + lm) * 32 + quad * 8);
        }
#pragma unroll
        for (int i = 0; i < 4; ++i)
#pragma unroll
            for (int j = 0; j < 4; ++j)
                acc[i][j] = __builtin_amdgcn_mfma_f32_16x16x32_bf16(af[i], bfr[j], acc[i][j], 0, 0, 0);
    }

#pragma unroll
    for (int i = 0; i < 4; ++i) {
        const int r0 = m0 + wm * 64 + i * 16 + quad * 4;
#pragma unroll
        for (int j = 0; j < 4; ++j) {
            const int col = n0 + wn * 64 + j * 16 + lm;
            const float bvj = bf2f(bias[col]);
#pragma unroll
            for (int r = 0; r < 4; ++r) {
                float v = acc[i][j][r] + bvj;
                if (RELU) v = fmaxf(v, 0.f);
                if (F32OUT) ((float*)Cv)[(size_t)(r0 + r) * N + col] = v;
                else        ((uint16_t*)Cv)[(size_t)(r0 + r) * N + col] = f2bf(v);
            }
        }
    }
}

// ---------------------------------------------------------------------------
// Staged GEMM 64x128 tile (small-N GEMMs -> 2 blocks/CU)
// ---------------------------------------------------------------------------
template<int RELU, int F32OUT>
__global__ __launch_bounds__(256)
void gemm_k64(const uint16_t* __restrict__ A, const uint16_t* __restrict__ Bt,
              const uint16_t* __restrict__ bias, void* __restrict__ Cv,
              int M, int N, int K)
{
    __shared__ __align__(16) uint16_t lsA[64 * 32];
    __shared__ __align__(16) uint16_t lsB[128 * 32];

    const int tid = threadIdx.x, lane = tid & 63, wid = tid >> 6;
    const int quad = lane >> 4, lm = lane & 15;
    const int wm = wid >> 1, wn = wid & 1;
    const int m0 = blockIdx.y * 64, n0 = blockIdx.x * 128;

    f32x4 acc[2][4];
#pragma unroll
    for (int i = 0; i < 2; ++i)
#pragma unroll
        for (int j = 0; j < 4; ++j) acc[i][j] = (f32x4){0.f, 0.f, 0.f, 0.f};

    const int rowA = tid >> 2;
    const int rowB0 = tid >> 2, rowB1 = (256 + tid) >> 2, cg = tid & 3;

    for (int k0 = 0; k0 < K; k0 += 32) {
        __syncthreads();
        gld_lds16(A  + (size_t)(m0 + rowA) * K + k0 + cg * 8, lsA + (size_t)tid * 8);
        gld_lds16(Bt + (size_t)(n0 + rowB0) * K + k0 + cg * 8, lsB + (size_t)tid * 8);
        gld_lds16(Bt + (size_t)(n0 + rowB1) * K + k0 + cg * 8, lsB + (size_t)(256 + tid) * 8);
        __syncthreads();

        bf16x8 af[2], bfr[4];
#pragma unroll
        for (int t = 0; t < 2; ++t)
            af[t] = *(const bf16x8*)(lsA + (wm * 32 + t * 16 + lm) * 32 + quad * 8);
#pragma unroll
        for (int t = 0; t < 4; ++t)
            bfr[t] = *(const bf16x8*)(lsB + (wn * 64 + t * 16 + lm) * 32 + quad * 8);
#pragma unroll
        for (int i = 0; i < 2; ++i)
#pragma unroll
            for (int j = 0; j < 4; ++j)
                acc[i][j] = __builtin_amdgcn_mfma_f32_16x16x32_bf16(af[i], bfr[j], acc[i][j], 0, 0, 0);
    }

#pragma unroll
    for (int i = 0; i < 2; ++i) {
        const int r0 = m0 + wm * 32 + i * 16 + quad * 4;
#pragma unroll
        for (int j = 0; j < 4; ++j) {
            const int col = n0 + wn * 64 + j * 16 + lm;
            const float bvj = bf2f(bias[col]);
#pragma unroll
            for (int r = 0; r < 4; ++r) {
                float v = acc[i][j][r] + bvj;
                if (RELU) v = fmaxf(v, 0.f);
                if (F32OUT) ((float*)Cv)[(size_t)(r0 + r) * N + col] = v;
                else        ((uint16_t*)Cv)[(size_t)(r0 + r) * N + col] = f2bf(v);
            }
        }
    }
}

// ---------------------------------------------------------------------------
// Staged QKV GEMM: parts 0,1 (Q,K) -> qk[8192][1024]; part 2 (V) -> Vt
// transposed [32][64][2048] (plain key order).
// ---------------------------------------------------------------------------
__global__ __launch_bounds__(256)
void gemm_qkv_s(const uint16_t* __restrict__ A, const uint16_t* __restrict__ Bt,
                const uint16_t* __restrict__ bq, const uint16_t* __restrict__ bk,
                const uint16_t* __restrict__ bv_,
                uint16_t* __restrict__ qk, uint16_t* __restrict__ Vt)
{
    __shared__ __align__(16) uint16_t lsA[128 * 32];
    __shared__ __align__(16) uint16_t lsB[128 * 32];

    const int tid = threadIdx.x, lane = tid & 63, wid = tid >> 6;
    const int quad = lane >> 4, lm = lane & 15;
    const int wm = wid >> 1, wn = wid & 1;
    const int m0 = blockIdx.y * 128, n0 = blockIdx.x * 128;
    const int part = n0 >> 9;
    const uint16_t* B = (part == 0) ? bq : (part == 1) ? bk : bv_;
    const int K = 512;

    f32x4 acc[4][4];
#pragma unroll
    for (int i = 0; i < 4; ++i)
#pragma unroll
        for (int j = 0; j < 4; ++j) acc[i][j] = (f32x4){0.f, 0.f, 0.f, 0.f};

    const int row0 = tid >> 2, row1 = (256 + tid) >> 2, cg = tid & 3;

    for (int k0 = 0; k0 < K; k0 += 32) {
        __syncthreads();
        gld_lds16(A  + (size_t)(m0 + row0) * K + k0 + cg * 8, lsA + (size_t)tid * 8);
        gld_lds16(A  + (size_t)(m0 + row1) * K + k0 + cg * 8, lsA + (size_t)(256 + tid) * 8);
        gld_lds16(Bt + (size_t)(n0 + row0) * K + k0 + cg * 8, lsB + (size_t)tid * 8);
        gld_lds16(Bt + (size_t)(n0 + row1) * K + k0 + cg * 8, lsB + (size_t)(256 + tid) * 8);
        __syncthreads();

        bf16x8 af[4], bfr[4];
#pragma unroll
        for (int t = 0; t < 4; ++t) {
            af[t]  = *(const bf16x8*)(lsA + (wm * 64 + t * 16 + lm) * 32 + quad * 8);
            bfr[t] = *(const bf16x8*)(lsB + (wn * 64 + t * 16 + lm) * 32 + quad * 8);
        }
#pragma unroll
        for (int i = 0; i < 4; ++i)
#pragma unroll
            for (int j = 0; j < 4; ++j)
                acc[i][j] = __builtin_amdgcn_mfma_f32_16x16x32_bf16(af[i], bfr[j], acc[i][j], 0, 0, 0);
    }

#pragma unroll
    for (int i = 0; i < 4; ++i) {
        const int mb = m0 + wm * 64 + i * 16 + quad * 4;
#pragma unroll
        for (int j = 0; j < 4; ++j) {
            const int nl = (n0 & 511) + wn * 64 + j * 16 + lm;
            const float bvj = bf2f(B[nl]);
            if (part < 2) {
#pragma unroll
                for (int r = 0; r < 4; ++r)
                    qk[(size_t)(mb + r) * 1024 + part * 512 + nl] = f2bf(acc[i][j][r] + bvj);
            } else {
                const int h = nl >> 6, d = nl & 63;
                const int b = mb >> 11, s0 = mb & 2047;
                const size_t base = ((size_t)(((b << 3) | h)) * 64 + d) * 2048 + s0;
#pragma unroll
                for (int r = 0; r < 4; ++r)
                    Vt[base + r] = f2bf(acc[i][j][r] + bvj);
            }
        }
    }
}

// ---------------------------------------------------------------------------
// Flash attention, inverse band mask (|i-j|<=5 excluded). Fixed-scale softmax.
// Grid (16, 32): 128 q-rows/block, 4 waves; wave w owns q-rows [w*32, w*32+32).
// K/V staged via global_load_lds with XOR-swizzled 16B chunks:
//   lsK[r][pc], pc = c ^ (r&7)   (8 chunks/row,  row = key,  64 d)
//   lsV[d][pc], pc = c ^ (d&15)  (16 chunks/row, row = d,   128 keys)
// -> DMA staging (no ds_writes, no VGPR round-trip), bank-uniform reads.
// lsP separate (stride 136, 16B-aligned) -> no union barrier. 2 barriers/iter.
// LDS 66 KB -> 2 blocks/CU.
// ---------------------------------------------------------------------------
__global__ __launch_bounds__(256, 2)
void attn_k(const uint16_t* __restrict__ qk, const uint16_t* __restrict__ Vt,
            uint16_t* __restrict__ Out)
{
    __shared__ __align__(16) uint16_t lsK[128 * 64];
    __shared__ __align__(16) uint16_t lsV[64 * 128];
    __shared__ __align__(16) uint16_t lsP[128 * 136];

    const int tid = threadIdx.x, lane = tid & 63, wid = tid >> 6;
    const int quad = lane >> 4, lm = lane & 15;
    const int bh = blockIdx.y, b = bh >> 3, h = bh & 7;
    const int q0 = blockIdx.x * 128;
    const float cscale = 0.125f * 1.44269504088896f;   // (1/sqrt(64))*log2(e)

    // Q fragments (wave-private 32 rows = 2 m-tiles), pre-scaled into log2 domain
    bf16x8 qf[2][2];
#pragma unroll
    for (int i = 0; i < 2; ++i)
#pragma unroll
        for (int ks = 0; ks < 2; ++ks) {
            bf16x8 q = *(const bf16x8*)(qk +
                (size_t)(b * 2048 + q0 + wid * 32 + i * 16 + lm) * 1024 + h * 64 + ks * 32 + quad * 8);
#pragma unroll
            for (int e = 0; e < 8; ++e)
                q[e] = (short)f2bf(bf2f((uint16_t)q[e]) * cscale);
            qf[i][ks] = q;
        }

    f32x4 oacc[2][4];
#pragma unroll
    for (int i = 0; i < 2; ++i)
#pragma unroll
        for (int n = 0; n < 4; ++n) oacc[i][n] = (f32x4){0.f, 0.f, 0.f, 0.f};
    float lrow[2][4];
#pragma unroll
    for (int i = 0; i < 2; ++i)
#pragma unroll
        for (int r = 0; r < 4; ++r) lrow[i][r] = 0.f;

    for (int j0 = 0; j0 < 2048; j0 += 128) {
        __syncthreads();   // prev-iter lsK/lsV reads done before restaging
        // stage K [128 keys][64 d]: chunk = r*8 + pc, pc = c ^ (r&7)
#pragma unroll
        for (int c4 = 0; c4 < 4; ++c4) {
            const int chunk = c4 * 256 + tid;
            const int r = chunk >> 3, lc = (chunk & 7) ^ (r & 7);
            gld_lds16(qk + (size_t)(b * 2048 + j0 + r) * 1024 + 512 + h * 64 + lc * 8,
                      lsK + (size_t)chunk * 8);
        }
        // stage V [64 d][128 keys]: chunk = d*16 + pc, pc = c ^ (d&15)
#pragma unroll
        for (int c4 = 0; c4 < 4; ++c4) {
            const int chunk = c4 * 256 + tid;
            const int d = chunk >> 4, lc = (chunk & 15) ^ (d & 15);
            gld_lds16(Vt + (size_t)(bh * 64 + d) * 2048 + j0 + lc * 8,
                      lsV + (size_t)chunk * 8);
        }
        __syncthreads();   // drains vmcnt (compiler) + all waves staged

        // S = Q K^T  (2 q-tiles x 8 key-tiles x 2 k-steps)
        f32x4 sacc[2][8];
#pragma unroll
        for (int i = 0; i < 2; ++i)
#pragma unroll
            for (int j = 0; j < 8; ++j) sacc[i][j] = (f32x4){0.f, 0.f, 0.f, 0.f};
#pragma unroll
        for (int ks = 0; ks < 2; ++ks)
#pragma unroll
            for (int j = 0; j < 8; ++j) {
                const int pc = (ks * 4 + quad) ^ (lm & 7);
                bf16x8 kf = *(const bf16x8*)(lsK + (j * 16 + lm) * 64 + pc * 8);
#pragma unroll
                for (int i = 0; i < 2; ++i)
                    sacc[i][j] = __builtin_amdgcn_mfma_f32_16x16x32_bf16(qf[i][ks], kf, sacc[i][j], 0, 0, 0);
            }

        // band mask (uniform branch; hits <=2 j0-tiles per block)
        if ((j0 + 127 >= q0 - 5) && (j0 <= q0 + 127 + 5)) {
#pragma unroll
            for (int i = 0; i < 2; ++i)
#pragma unroll
                for (int j = 0; j < 8; ++j)
#pragma unroll
                    for (int r = 0; r < 4; ++r) {
                        int qr = q0 + wid * 32 + i * 16 + quad * 4 + r;
                        int kc = j0 + j * 16 + lm;
                        int dd = qr - kc; if (dd < 0) dd = -dd;
                        if (dd <= 5) sacc[i][j][r] = -1e30f;
                    }
        }

        // p = exp2(s); accumulate l; write P (wave-private rows, no barrier)
#pragma unroll
        for (int i = 0; i < 2; ++i)
#pragma unroll
            for (int r = 0; r < 4; ++r) {
                const int prow = wid * 32 + i * 16 + quad * 4 + r;
                float p[8], rs = 0.f;
#pragma unroll
                for (int j = 0; j < 8; ++j) { p[j] = exp2f(sacc[i][j][r]); rs += p[j]; }
                lrow[i][r] += rs;
#pragma unroll
                for (int jp = 0; jp < 4; ++jp) {
                    uint32_t u = pk2bf(p[2 * jp], p[2 * jp + 1]);
                    lsP[prow * 136 + (2 * jp) * 16 + lm]     = (uint16_t)u;
                    lsP[prow * 136 + (2 * jp + 1) * 16 + lm] = (uint16_t)(u >> 16);
                }
            }

        // O += P V   (vf chunks XOR-swizzled: pc = (ks*4+quad) ^ lm)
#pragma unroll
        for (int ks = 0; ks < 4; ++ks) {
            bf16x8 pa[2];
#pragma unroll
            for (int i = 0; i < 2; ++i)
                pa[i] = *(const bf16x8*)(lsP + (wid * 32 + i * 16 + lm) * 136 + ks * 32 + quad * 8);
#pragma unroll
            for (int n = 0; n < 4; ++n) {
                const int pc = (ks * 4 + quad) ^ lm;
                bf16x8 vf = *(const bf16x8*)(lsV + (n * 16 + lm) * 128 + pc * 8);
#pragma unroll
                for (int i = 0; i < 2; ++i)
                    oacc[i][n] = __builtin_amdgcn_mfma_f32_16x16x32_bf16(pa[i], vf, oacc[i][n], 0, 0, 0);
            }
        }
    }

#pragma unroll
    for (int i = 0; i < 2; ++i)
#pragma unroll
        for (int r = 0; r < 4; ++r) {
            float l = lrow[i][r];
            l += __shfl_xor(l, 1, 16);
            l += __shfl_xor(l, 2, 16);
            l += __shfl_xor(l, 4, 16);
            l += __shfl_xor(l, 8, 16);
            const float inv = 1.f / (l + 1e-30f);
            const int s = q0 + wid * 32 + i * 16 + quad * 4 + r;
#pragma unroll
            for (int n = 0; n < 4; ++n)
                Out[(size_t)(b * 2048 + s) * 512 + h * 64 + n * 16 + lm] = f2bf(oacc[i][n][r] * inv);
        }
}

// ---------------------------------------------------------------------------
// Launch — fp32 in, fp32 out; ws peak 37 MiB; 6 dispatches total
// ---------------------------------------------------------------------------
extern "C" void kernel_launch(void* const* d_in, const int* in_sizes, int n_in,
                              void* d_out, int out_size, void* d_ws, size_t ws_size,
                              hipStream_t stream)
{
    const float* x  = (const float*)d_in[0];
    const float* W1 = (const float*)d_in[1];
    const float* b1 = (const float*)d_in[2];
    const float* W2 = (const float*)d_in[3];
    const float* b2 = (const float*)d_in[4];
    const float* Wq = (const float*)d_in[5];
    const float* bq = (const float*)d_in[6];
    const float* Wk = (const float*)d_in[7];
    const float* bk = (const float*)d_in[8];
    const float* Wv = (const float*)d_in[9];
    const float* bv = (const float*)d_in[10];
    const float* Wo = (const float*)d_in[11];
    const float* bo = (const float*)d_in[12];
    (void)in_sizes; (void)n_in; (void)out_size; (void)ws_size;

    char* ws = (char*)d_ws;
    const size_t MiB = 1024 * 1024;
    uint16_t* xb    = (uint16_t*)(ws + 0);                       // 8 MiB [dead after G1]
    uint16_t* W1T   = (uint16_t*)(ws + 8 * MiB);                 // 1 MiB  [1024][512]
    uint16_t* W2T   = (uint16_t*)(ws + 9 * MiB);                 // 1 MiB  [512][1024]
    uint16_t* WqkvT = (uint16_t*)(ws + 10 * MiB);                // 1.5 MiB [1536][512]
    uint16_t* WoT   = (uint16_t*)(ws + 11 * MiB + 512 * 1024);   // 0.5 MiB [512][512]
    uint16_t* bbase = (uint16_t*)(ws + 12 * MiB);                // 3584 u16
    uint16_t* b1b = bbase, *b2b = bbase + 1024, *bqb = bbase + 1536;
    uint16_t* bkb = bbase + 2048, *bvb = bbase + 2560, *bob = bbase + 3072;
    uint16_t* xm1   = (uint16_t*)(ws + 13 * MiB);                // 16 MiB [13,29)
    uint16_t* xm    = (uint16_t*)(ws + 29 * MiB);                //  8 MiB [29,37)
    uint16_t* qk    = xm1;   // aliases xm1 (dead after G2)
    uint16_t* att   = xm;    // aliases xm  (dead after QKV gemm)
    uint16_t* Vt    = xb;    // aliases xb  (dead after G1)

    prep_all<<<6158, dim3(32, 8), 0, stream>>>(x, W1, W2, Wq, Wk, Wv, Wo,
                                               b1, b2, bq, bk, bv, bo,
                                               W1T, W2T, WqkvT, WoT, xb, bbase);

    gemm_k<1,0>  <<<dim3(8, 64),  256, 0, stream>>>(xb,  W1T, b1b, xm1, 8192, 1024, 512);
    gemm_k64<0,0><<<dim3(4, 128), 256, 0, stream>>>(xm1, W2T, b2b, xm,  8192, 512, 1024);
    gemm_qkv_s   <<<dim3(12, 64), 256, 0, stream>>>(xm, WqkvT, bqb, bkb, bvb, qk, Vt);
    attn_k       <<<dim3(16, 32), 256, 0, stream>>>(qk, Vt, att);
    gemm_k64<0,1><<<dim3(4, 128), 256, 0, stream>>>(att, WoT, bob, d_out, 8192, 512, 512);
}

// Round 12
// 225.431 us; speedup vs baseline: 1.1730x; 1.1146x over previous
//
#include <hip/hip_runtime.h>
#include <stdint.h>

typedef __attribute__((ext_vector_type(8))) short bf16x8;
typedef __attribute__((ext_vector_type(4))) float f32x4;

__device__ __forceinline__ float bf2f(uint16_t u) {
    union { uint32_t u; float f; } c; c.u = ((uint32_t)u) << 16; return c.f;
}
__device__ __forceinline__ uint16_t f2bf(float f) {
    union { float f; uint32_t u; } c; c.f = f;
    uint32_t r = c.u + 0x7fffu + ((c.u >> 16) & 1u);
    return (uint16_t)(r >> 16);
}
__device__ __forceinline__ uint32_t pk2bf(float a, float b) {
#if __has_builtin(__builtin_amdgcn_cvt_pk_bf16_f32)
    auto v = __builtin_amdgcn_cvt_pk_bf16_f32(a, b);
    uint32_t u; __builtin_memcpy(&u, &v, 4); return u;
#else
    return (uint32_t)f2bf(a) | ((uint32_t)f2bf(b) << 16);
#endif
}
// raw v_exp_f32 (no OCML wrapper); exp2(-huge) -> 0 correctly
__device__ __forceinline__ float fexp2(float x) {
#if __has_builtin(__builtin_amdgcn_exp2f)
    return __builtin_amdgcn_exp2f(x);
#else
    return exp2f(x);
#endif
}

// async global->LDS, 16B/lane; LDS dest must be wave-uniform base + lane*16.
__device__ __forceinline__ void gld_lds16(const uint16_t* g, uint16_t* l) {
    __builtin_amdgcn_global_load_lds(
        (const __attribute__((address_space(1))) void*)g,
        (__attribute__((address_space(3))) void*)l, 16, 0, 0);
}

// ---------------------------------------------------------------------------
// Single fused prep (weights transpose, x convert, bias convert)
// ---------------------------------------------------------------------------
__global__ void prep_all(const float* __restrict__ x,
                         const float* __restrict__ W1, const float* __restrict__ W2,
                         const float* __restrict__ Wq, const float* __restrict__ Wk,
                         const float* __restrict__ Wv, const float* __restrict__ Wo,
                         const float* __restrict__ b1, const float* __restrict__ b2,
                         const float* __restrict__ bq, const float* __restrict__ bk,
                         const float* __restrict__ bv, const float* __restrict__ bo,
                         uint16_t* __restrict__ W1T, uint16_t* __restrict__ W2T,
                         uint16_t* __restrict__ WqkvT, uint16_t* __restrict__ WoT,
                         uint16_t* __restrict__ xb, uint16_t* __restrict__ bbase)
{
    const int id = blockIdx.x;
    const int tx = threadIdx.x, ty = threadIdx.y;
    const int tid = ty * 32 + tx;
    if (id < 2048) {
        __shared__ uint16_t t[32][33];
        const float* src; uint16_t* dst; int R, C, tile;
        if      (id < 512)  { src = W1; dst = W1T;              R = 512;  C = 1024; tile = id; }
        else if (id < 1024) { src = W2; dst = W2T;              R = 1024; C = 512;  tile = id - 512; }
        else if (id < 1280) { src = Wq; dst = WqkvT;            R = 512;  C = 512;  tile = id - 1024; }
        else if (id < 1536) { src = Wk; dst = WqkvT + 512*512;  R = 512;  C = 512;  tile = id - 1280; }
        else if (id < 1792) { src = Wv; dst = WqkvT + 1024*512; R = 512;  C = 512;  tile = id - 1536; }
        else                { src = Wo; dst = WoT;              R = 512;  C = 512;  tile = id - 1792; }
        const int ntx = C / 32;
        const int bx = (tile % ntx) * 32, by = (tile / ntx) * 32;
#pragma unroll
        for (int i = ty; i < 32; i += 8) t[i][tx] = f2bf(src[(size_t)(by + i) * C + bx + tx]);
        __syncthreads();
#pragma unroll
        for (int i = ty; i < 32; i += 8) dst[(size_t)(bx + i) * R + by + tx] = t[tx][i];
    } else if (id < 6144) {
        int i = (id - 2048) * 256 + tid;
        float4 v = ((const float4*)x)[i];
        ushort4 o;
        o.x = f2bf(v.x); o.y = f2bf(v.y); o.z = f2bf(v.z); o.w = f2bf(v.w);
        ((ushort4*)xb)[i] = o;
    } else {
        int i = (id - 6144) * 256 + tid;
        if      (i < 1024) bbase[i] = f2bf(b1[i]);
        else if (i < 1536) bbase[i] = f2bf(b2[i - 1024]);
        else if (i < 2048) bbase[i] = f2bf(bq[i - 1536]);
        else if (i < 2560) bbase[i] = f2bf(bk[i - 2048]);
        else if (i < 3072) bbase[i] = f2bf(bv[i - 2560]);
        else if (i < 3584) bbase[i] = f2bf(bo[i - 3072]);
    }
}

// ---------------------------------------------------------------------------
// Staged GEMM 128x128, BK=64, XOR-swizzled LDS (conflict-free ds_read_b128):
// physical chunk pc holds logical chunk pc ^ (row&7); 32 MFMA per barrier pair.
// ---------------------------------------------------------------------------
template<int RELU, int F32OUT>
__global__ __launch_bounds__(256)
void gemm_k(const uint16_t* __restrict__ A, const uint16_t* __restrict__ Bt,
            const uint16_t* __restrict__ bias, void* __restrict__ Cv,
            int M, int N, int K)
{
    __shared__ __align__(16) uint16_t lsA[128 * 64];
    __shared__ __align__(16) uint16_t lsB[128 * 64];

    const int tid = threadIdx.x, lane = tid & 63;
    const int wid = tid >> 6;
    const int quad = lane >> 4, lm = lane & 15;
    const int wm = wid >> 1, wn = wid & 1;
    const int m0 = blockIdx.y * 128, n0 = blockIdx.x * 128;

    f32x4 acc[4][4];
#pragma unroll
    for (int i = 0; i < 4; ++i)
#pragma unroll
        for (int j = 0; j < 4; ++j) acc[i][j] = (f32x4){0.f, 0.f, 0.f, 0.f};

    for (int k0 = 0; k0 < K; k0 += 64) {
        __syncthreads();
        // stage A,B tiles: 1024 chunks each, 4/thread; src col-group swizzled
#pragma unroll
        for (int c4 = 0; c4 < 4; ++c4) {
            const int chunk = c4 * 256 + tid;
            const int r = chunk >> 3, lc = (chunk & 7) ^ (r & 7);
            gld_lds16(A  + (size_t)(m0 + r) * K + k0 + lc * 8, lsA + (size_t)chunk * 8);
            gld_lds16(Bt + (size_t)(n0 + r) * K + k0 + lc * 8, lsB + (size_t)chunk * 8);
        }
        __syncthreads();

#pragma unroll
        for (int kh = 0; kh < 2; ++kh) {
            bf16x8 af[4], bfr[4];
#pragma unroll
            for (int t = 0; t < 4; ++t) {
                const int pcA = ((kh * 4 + quad) ^ (lm & 7));
                af[t]  = *(const bf16x8*)(lsA + (wm * 64 + t * 16 + lm) * 64 + pcA * 8);
                bfr[t] = *(const bf16x8*)(lsB + (wn * 64 + t * 16 + lm) * 64 + pcA * 8);
            }
#pragma unroll
            for (int i = 0; i < 4; ++i)
#pragma unroll
                for (int j = 0; j < 4; ++j)
                    acc[i][j] = __builtin_amdgcn_mfma_f32_16x16x32_bf16(af[i], bfr[j], acc[i][j], 0, 0, 0);
        }
    }

#pragma unroll
    for (int i = 0; i < 4; ++i) {
        const int r0 = m0 + wm * 64 + i * 16 + quad * 4;
#pragma unroll
        for (int j = 0; j < 4; ++j) {
            const int col = n0 + wn * 64 + j * 16 + lm;
            const float bvj = bf2f(bias[col]);
#pragma unroll
            for (int r = 0; r < 4; ++r) {
                float v = acc[i][j][r] + bvj;
                if (RELU) v = fmaxf(v, 0.f);
                if (F32OUT) ((float*)Cv)[(size_t)(r0 + r) * N + col] = v;
                else        ((uint16_t*)Cv)[(size_t)(r0 + r) * N + col] = f2bf(v);
            }
        }
    }
}

// ---------------------------------------------------------------------------
// Staged GEMM 64x128, BK=64, XOR-swizzled (small-N GEMMs -> 2 blocks/CU)
// ---------------------------------------------------------------------------
template<int RELU, int F32OUT>
__global__ __launch_bounds__(256)
void gemm_k64(const uint16_t* __restrict__ A, const uint16_t* __restrict__ Bt,
              const uint16_t* __restrict__ bias, void* __restrict__ Cv,
              int M, int N, int K)
{
    __shared__ __align__(16) uint16_t lsA[64 * 64];
    __shared__ __align__(16) uint16_t lsB[128 * 64];

    const int tid = threadIdx.x, lane = tid & 63;
    const int wid = tid >> 6;
    const int quad = lane >> 4, lm = lane & 15;
    const int wm = wid >> 1, wn = wid & 1;
    const int m0 = blockIdx.y * 64, n0 = blockIdx.x * 128;

    f32x4 acc[2][4];
#pragma unroll
    for (int i = 0; i < 2; ++i)
#pragma unroll
        for (int j = 0; j < 4; ++j) acc[i][j] = (f32x4){0.f, 0.f, 0.f, 0.f};

    for (int k0 = 0; k0 < K; k0 += 64) {
        __syncthreads();
#pragma unroll
        for (int c4 = 0; c4 < 2; ++c4) {          // A: 512 chunks
            const int chunk = c4 * 256 + tid;
            const int r = chunk >> 3, lc = (chunk & 7) ^ (r & 7);
            gld_lds16(A + (size_t)(m0 + r) * K + k0 + lc * 8, lsA + (size_t)chunk * 8);
        }
#pragma unroll
        for (int c4 = 0; c4 < 4; ++c4) {          // B: 1024 chunks
            const int chunk = c4 * 256 + tid;
            const int r = chunk >> 3, lc = (chunk & 7) ^ (r & 7);
            gld_lds16(Bt + (size_t)(n0 + r) * K + k0 + lc * 8, lsB + (size_t)chunk * 8);
        }
        __syncthreads();

#pragma unroll
        for (int kh = 0; kh < 2; ++kh) {
            const int pc = ((kh * 4 + quad) ^ (lm & 7));
            bf16x8 af[2], bfr[4];
#pragma unroll
            for (int t = 0; t < 2; ++t)
                af[t] = *(const bf16x8*)(lsA + (wm * 32 + t * 16 + lm) * 64 + pc * 8);
#pragma unroll
            for (int t = 0; t < 4; ++t)
                bfr[t] = *(const bf16x8*)(lsB + (wn * 64 + t * 16 + lm) * 64 + pc * 8);
#pragma unroll
            for (int i = 0; i < 2; ++i)
#pragma unroll
                for (int j = 0; j < 4; ++j)
                    acc[i][j] = __builtin_amdgcn_mfma_f32_16x16x32_bf16(af[i], bfr[j], acc[i][j], 0, 0, 0);
        }
    }

#pragma unroll
    for (int i = 0; i < 2; ++i) {
        const int r0 = m0 + wm * 32 + i * 16 + quad * 4;
#pragma unroll
        for (int j = 0; j < 4; ++j) {
            const int col = n0 + wn * 64 + j * 16 + lm;
            const float bvj = bf2f(bias[col]);
#pragma unroll
            for (int r = 0; r < 4; ++r) {
                float v = acc[i][j][r] + bvj;
                if (RELU) v = fmaxf(v, 0.f);
                if (F32OUT) ((float*)Cv)[(size_t)(r0 + r) * N + col] = v;
                else        ((uint16_t*)Cv)[(size_t)(r0 + r) * N + col] = f2bf(v);
            }
        }
    }
}

// ---------------------------------------------------------------------------
// Staged QKV GEMM (BK=64, swizzled): Q,K -> qk[8192][1024]; V -> Vt transposed.
// ---------------------------------------------------------------------------
__global__ __launch_bounds__(256)
void gemm_qkv_s(const uint16_t* __restrict__ A, const uint16_t* __restrict__ Bt,
                const uint16_t* __restrict__ bq, const uint16_t* __restrict__ bk,
                const uint16_t* __restrict__ bv_,
                uint16_t* __restrict__ qk, uint16_t* __restrict__ Vt)
{
    __shared__ __align__(16) uint16_t lsA[128 * 64];
    __shared__ __align__(16) uint16_t lsB[128 * 64];

    const int tid = threadIdx.x, lane = tid & 63;
    const int wid = tid >> 6;
    const int quad = lane >> 4, lm = lane & 15;
    const int wm = wid >> 1, wn = wid & 1;
    const int m0 = blockIdx.y * 128, n0 = blockIdx.x * 128;
    const int part = n0 >> 9;
    const uint16_t* B = (part == 0) ? bq : (part == 1) ? bk : bv_;
    const int K = 512;

    f32x4 acc[4][4];
#pragma unroll
    for (int i = 0; i < 4; ++i)
#pragma unroll
        for (int j = 0; j < 4; ++j) acc[i][j] = (f32x4){0.f, 0.f, 0.f, 0.f};

    for (int k0 = 0; k0 < K; k0 += 64) {
        __syncthreads();
#pragma unroll
        for (int c4 = 0; c4 < 4; ++c4) {
            const int chunk = c4 * 256 + tid;
            const int r = chunk >> 3, lc = (chunk & 7) ^ (r & 7);
            gld_lds16(A  + (size_t)(m0 + r) * K + k0 + lc * 8, lsA + (size_t)chunk * 8);
            gld_lds16(Bt + (size_t)(n0 + r) * K + k0 + lc * 8, lsB + (size_t)chunk * 8);
        }
        __syncthreads();

#pragma unroll
        for (int kh = 0; kh < 2; ++kh) {
            const int pc = ((kh * 4 + quad) ^ (lm & 7));
            bf16x8 af[4], bfr[4];
#pragma unroll
            for (int t = 0; t < 4; ++t) {
                af[t]  = *(const bf16x8*)(lsA + (wm * 64 + t * 16 + lm) * 64 + pc * 8);
                bfr[t] = *(const bf16x8*)(lsB + (wn * 64 + t * 16 + lm) * 64 + pc * 8);
            }
#pragma unroll
            for (int i = 0; i < 4; ++i)
#pragma unroll
                for (int j = 0; j < 4; ++j)
                    acc[i][j] = __builtin_amdgcn_mfma_f32_16x16x32_bf16(af[i], bfr[j], acc[i][j], 0, 0, 0);
        }
    }

#pragma unroll
    for (int i = 0; i < 4; ++i) {
        const int mb = m0 + wm * 64 + i * 16 + quad * 4;
#pragma unroll
        for (int j = 0; j < 4; ++j) {
            const int nl = (n0 & 511) + wn * 64 + j * 16 + lm;
            const float bvj = bf2f(B[nl]);
            if (part < 2) {
#pragma unroll
                for (int r = 0; r < 4; ++r)
                    qk[(size_t)(mb + r) * 1024 + part * 512 + nl] = f2bf(acc[i][j][r] + bvj);
            } else {
                const int h = nl >> 6, d = nl & 63;
                const int b = mb >> 11, s0 = mb & 2047;
                const size_t base = ((size_t)(((b << 3) | h)) * 64 + d) * 2048 + s0;
#pragma unroll
                for (int r = 0; r < 4; ++r)
                    Vt[base + r] = f2bf(acc[i][j][r] + bvj);
            }
        }
    }
}

// ---------------------------------------------------------------------------
// Flash attention, inverse band mask (|i-j|<=5 excluded). Fixed-scale softmax
// with raw v_exp_f32. DMA-staged XOR-swizzled K/V. 2 barriers/iter.
// Grid (16, 32): 128 q-rows/block, 4 waves; wave w owns q-rows [w*32, w*32+32).
// ---------------------------------------------------------------------------
__global__ __launch_bounds__(256, 2)
void attn_k(const uint16_t* __restrict__ qk, const uint16_t* __restrict__ Vt,
            uint16_t* __restrict__ Out)
{
    __shared__ __align__(16) uint16_t lsK[128 * 64];
    __shared__ __align__(16) uint16_t lsV[64 * 128];
    __shared__ __align__(16) uint16_t lsP[128 * 136];

    const int tid = threadIdx.x, lane = tid & 63, wid = tid >> 6;
    const int quad = lane >> 4, lm = lane & 15;
    const int bh = blockIdx.y, b = bh >> 3, h = bh & 7;
    const int q0 = blockIdx.x * 128;
    const float cscale = 0.125f * 1.44269504088896f;   // (1/sqrt(64))*log2(e)

    bf16x8 qf[2][2];
#pragma unroll
    for (int i = 0; i < 2; ++i)
#pragma unroll
        for (int ks = 0; ks < 2; ++ks) {
            bf16x8 q = *(const bf16x8*)(qk +
                (size_t)(b * 2048 + q0 + wid * 32 + i * 16 + lm) * 1024 + h * 64 + ks * 32 + quad * 8);
#pragma unroll
            for (int e = 0; e < 8; ++e)
                q[e] = (short)f2bf(bf2f((uint16_t)q[e]) * cscale);
            qf[i][ks] = q;
        }

    f32x4 oacc[2][4];
#pragma unroll
    for (int i = 0; i < 2; ++i)
#pragma unroll
        for (int n = 0; n < 4; ++n) oacc[i][n] = (f32x4){0.f, 0.f, 0.f, 0.f};
    float lrow[2][4];
#pragma unroll
    for (int i = 0; i < 2; ++i)
#pragma unroll
        for (int r = 0; r < 4; ++r) lrow[i][r] = 0.f;

    for (int j0 = 0; j0 < 2048; j0 += 128) {
        __syncthreads();
        // stage K [128 keys][64 d]: chunk = r*8 + pc, pc = c ^ (r&7)
#pragma unroll
        for (int c4 = 0; c4 < 4; ++c4) {
            const int chunk = c4 * 256 + tid;
            const int r = chunk >> 3, lc = (chunk & 7) ^ (r & 7);
            gld_lds16(qk + (size_t)(b * 2048 + j0 + r) * 1024 + 512 + h * 64 + lc * 8,
                      lsK + (size_t)chunk * 8);
        }
        // stage V [64 d][128 keys]: chunk = d*16 + pc, pc = c ^ (d&15)
#pragma unroll
        for (int c4 = 0; c4 < 4; ++c4) {
            const int chunk = c4 * 256 + tid;
            const int d = chunk >> 4, lc = (chunk & 15) ^ (d & 15);
            gld_lds16(Vt + (size_t)(bh * 64 + d) * 2048 + j0 + lc * 8,
                      lsV + (size_t)chunk * 8);
        }
        __syncthreads();

        // S = Q K^T
        f32x4 sacc[2][8];
#pragma unroll
        for (int i = 0; i < 2; ++i)
#pragma unroll
            for (int j = 0; j < 8; ++j) sacc[i][j] = (f32x4){0.f, 0.f, 0.f, 0.f};
#pragma unroll
        for (int ks = 0; ks < 2; ++ks)
#pragma unroll
            for (int j = 0; j < 8; ++j) {
                const int pc = (ks * 4 + quad) ^ (lm & 7);
                bf16x8 kf = *(const bf16x8*)(lsK + (j * 16 + lm) * 64 + pc * 8);
#pragma unroll
                for (int i = 0; i < 2; ++i)
                    sacc[i][j] = __builtin_amdgcn_mfma_f32_16x16x32_bf16(qf[i][ks], kf, sacc[i][j], 0, 0, 0);
            }

        // band mask (uniform branch)
        if ((j0 + 127 >= q0 - 5) && (j0 <= q0 + 127 + 5)) {
#pragma unroll
            for (int i = 0; i < 2; ++i)
#pragma unroll
                for (int j = 0; j < 8; ++j)
#pragma unroll
                    for (int r = 0; r < 4; ++r) {
                        int qr = q0 + wid * 32 + i * 16 + quad * 4 + r;
                        int kc = j0 + j * 16 + lm;
                        int dd = qr - kc; if (dd < 0) dd = -dd;
                        if (dd <= 5) sacc[i][j][r] = -1e30f;
                    }
        }

        // p = exp2(s) (raw v_exp_f32); accumulate l; write P (wave-private rows)
#pragma unroll
        for (int i = 0; i < 2; ++i)
#pragma unroll
            for (int r = 0; r < 4; ++r) {
                const int prow = wid * 32 + i * 16 + quad * 4 + r;
                float p[8], rs = 0.f;
#pragma unroll
                for (int j = 0; j < 8; ++j) { p[j] = fexp2(sacc[i][j][r]); rs += p[j]; }
                lrow[i][r] += rs;
#pragma unroll
                for (int jp = 0; jp < 4; ++jp) {
                    uint32_t u = pk2bf(p[2 * jp], p[2 * jp + 1]);
                    lsP[prow * 136 + (2 * jp) * 16 + lm]     = (uint16_t)u;
                    lsP[prow * 136 + (2 * jp + 1) * 16 + lm] = (uint16_t)(u >> 16);
                }
            }

        // O += P V
#pragma unroll
        for (int ks = 0; ks < 4; ++ks) {
            bf16x8 pa[2];
#pragma unroll
            for (int i = 0; i < 2; ++i)
                pa[i] = *(const bf16x8*)(lsP + (wid * 32 + i * 16 + lm) * 136 + ks * 32 + quad * 8);
#pragma unroll
            for (int n = 0; n < 4; ++n) {
                const int pc = (ks * 4 + quad) ^ lm;
                bf16x8 vf = *(const bf16x8*)(lsV + (n * 16 + lm) * 128 + pc * 8);
#pragma unroll
                for (int i = 0; i < 2; ++i)
                    oacc[i][n] = __builtin_amdgcn_mfma_f32_16x16x32_bf16(pa[i], vf, oacc[i][n], 0, 0, 0);
            }
        }
    }

#pragma unroll
    for (int i = 0; i < 2; ++i)
#pragma unroll
        for (int r = 0; r < 4; ++r) {
            float l = lrow[i][r];
            l += __shfl_xor(l, 1, 16);
            l += __shfl_xor(l, 2, 16);
            l += __shfl_xor(l, 4, 16);
            l += __shfl_xor(l, 8, 16);
            const float inv = 1.f / (l + 1e-30f);
            const int s = q0 + wid * 32 + i * 16 + quad * 4 + r;
#pragma unroll
            for (int n = 0; n < 4; ++n)
                Out[(size_t)(b * 2048 + s) * 512 + h * 64 + n * 16 + lm] = f2bf(oacc[i][n][r] * inv);
        }
}

// ---------------------------------------------------------------------------
// Launch — fp32 in, fp32 out; ws peak 37 MiB; 6 dispatches total
// ---------------------------------------------------------------------------
extern "C" void kernel_launch(void* const* d_in, const int* in_sizes, int n_in,
                              void* d_out, int out_size, void* d_ws, size_t ws_size,
                              hipStream_t stream)
{
    const float* x  = (const float*)d_in[0];
    const float* W1 = (const float*)d_in[1];
    const float* b1 = (const float*)d_in[2];
    const float* W2 = (const float*)d_in[3];
    const float* b2 = (const float*)d_in[4];
    const float* Wq = (const float*)d_in[5];
    const float* bq = (const float*)d_in[6];
    const float* Wk = (const float*)d_in[7];
    const float* bk = (const float*)d_in[8];
    const float* Wv = (const float*)d_in[9];
    const float* bv = (const float*)d_in[10];
    const float* Wo = (const float*)d_in[11];
    const float* bo = (const float*)d_in[12];
    (void)in_sizes; (void)n_in; (void)out_size; (void)ws_size;

    char* ws = (char*)d_ws;
    const size_t MiB = 1024 * 1024;
    uint16_t* xb    = (uint16_t*)(ws + 0);                       // 8 MiB [dead after G1]
    uint16_t* W1T   = (uint16_t*)(ws + 8 * MiB);                 // 1 MiB  [1024][512]
    uint16_t* W2T   = (uint16_t*)(ws + 9 * MiB);                 // 1 MiB  [512][1024]
    uint16_t* WqkvT = (uint16_t*)(ws + 10 * MiB);                // 1.5 MiB [1536][512]
    uint16_t* WoT   = (uint16_t*)(ws + 11 * MiB + 512 * 1024);   // 0.5 MiB [512][512]
    uint16_t* bbase = (uint16_t*)(ws + 12 * MiB);                // 3584 u16
    uint16_t* b1b = bbase, *b2b = bbase + 1024, *bqb = bbase + 1536;
    uint16_t* bkb = bbase + 2048, *bvb = bbase + 2560, *bob = bbase + 3072;
    uint16_t* xm1   = (uint16_t*)(ws + 13 * MiB);                // 16 MiB [13,29)
    uint16_t* xm    = (uint16_t*)(ws + 29 * MiB);                //  8 MiB [29,37)
    uint16_t* qk    = xm1;   // aliases xm1 (dead after G2)
    uint16_t* att   = xm;    // aliases xm  (dead after QKV gemm)
    uint16_t* Vt    = xb;    // aliases xb  (dead after G1)

    prep_all<<<6158, dim3(32, 8), 0, stream>>>(x, W1, W2, Wq, Wk, Wv, Wo,
                                               b1, b2, bq, bk, bv, bo,
                                               W1T, W2T, WqkvT, WoT, xb, bbase);

    gemm_k<1,0>  <<<dim3(8, 64),  256, 0, stream>>>(xb,  W1T, b1b, xm1, 8192, 1024, 512);
    gemm_k64<0,0><<<dim3(4, 128), 256, 0, stream>>>(xm1, W2T, b2b, xm,  8192, 512, 1024);
    gemm_qkv_s   <<<dim3(12, 64), 256, 0, stream>>>(xm, WqkvT, bqb, bkb, bvb, qk, Vt);
    attn_k       <<<dim3(16, 32), 256, 0, stream>>>(qk, Vt, att);
    gemm_k64<0,1><<<dim3(4, 128), 256, 0, stream>>>(att, WoT, bob, d_out, 8192, 512, 512);
}